// Round 1
// baseline (324.202 us; speedup 1.0000x reference)
//
#include <hip/hip_runtime.h>

// YOLO-v1 loss, N=4096, S=14 grid, 30 channels/cell.
// Memory-bound streaming reduction: ~176 MB in, 5 floats out. HBM floor ~28us.

#define NBATCH   4096
#define SGRID    14
#define CELLS    (NBATCH * SGRID * SGRID)   // 802816
#define CPB      256                        // cells per block (divides CELLS exactly: 3136 blocks)
#define NBLK     (CELLS / CPB)              // 3136
#define L_COORD  5.0f
#define L_NOOBJ  0.5f

__global__ __launch_bounds__(256) void yolo_main(
    const float* __restrict__ pred,    // [CELLS][30]
    const float* __restrict__ tbox,    // [CELLS][4]
    const float* __restrict__ tcls,    // [CELLS][20]
    const int*   __restrict__ objmap,  // [CELLS] (bool as int32)
    float*       __restrict__ ws)      // [4]: reg, contain, noobj, cls (pre-scaled)
{
    __shared__ float lds_pred[CPB * 30];   // 30720 B
    __shared__ float lds_obj[CPB];
    __shared__ float red[4][4];            // [wave][term]

    const int tid  = threadIdx.x;
    const int blk  = blockIdx.x;
    const int base = blk * CPB;

    // ---- stage pred tile: 1920 float4, fully coalesced ----
    {
        const float4* p4  = (const float4*)pred + (size_t)blk * (CPB * 30 / 4);
        float4*       lp4 = (float4*)lds_pred;
        for (int i = tid; i < CPB * 30 / 4; i += 256)   // 7-8 iters
            lp4[i] = p4[i];
    }
    lds_obj[tid] = objmap[base + tid] ? 1.0f : 0.0f;
    __syncthreads();

    float acc_reg = 0.f, acc_cont = 0.f, acc_noobj = 0.f, acc_cls = 0.f;

    // ---- cls pass: coalesced float4 stream over target_cls ----
    {
        const float4* c4 = (const float4*)tcls + (size_t)blk * (CPB * 20 / 4);
        for (int i = tid; i < CPB * 20 / 4; i += 256) {  // exactly 5 iters
            float4 t  = c4[i];
            int cell  = i / 5;                // 5 float4 per cell (20 ch)
            int ch0   = (i - cell * 5) * 4;
            float o   = lds_obj[cell];
            const float* pc = &lds_pred[cell * 30 + 10 + ch0];
            float d0 = pc[0] - t.x, d1 = pc[1] - t.y;
            float d2 = pc[2] - t.z, d3 = pc[3] - t.w;
            acc_cls += o * (d0*d0 + d1*d1 + d2*d2 + d3*d3);
        }
    }

    // ---- per-cell pass: boxes / iou / noobj ----
    {
        const float* pp = &lds_pred[tid * 30];  // stride 30 -> 2-way bank alias (free)
        float x1 = pp[0], y1 = pp[1], w1 = pp[2], h1 = pp[3], c1 = pp[4];
        float x2 = pp[5], y2 = pp[6], w2 = pp[7], h2 = pp[8], c2 = pp[9];
        float o  = lds_obj[tid];
        float no = 1.0f - o;
        acc_noobj = no * (c1*c1 + c2*c2);

        float4 tb = ((const float4*)tbox)[base + tid];  // coalesced
        const float invS = 1.0f / 14.0f;

        // target xyxy
        float txc = tb.x * invS, tyc = tb.y * invS;
        float tx1 = txc - 0.5f * tb.z, ty1 = tyc - 0.5f * tb.w;
        float tx2 = txc + 0.5f * tb.z, ty2 = tyc + 0.5f * tb.w;
        float ta  = (tx2 - tx1) * (ty2 - ty1);

        // box1 iou
        float ax1 = x1 * invS - 0.5f * w1, ay1 = y1 * invS - 0.5f * h1;
        float ax2 = x1 * invS + 0.5f * w1, ay2 = y1 * invS + 0.5f * h1;
        float a1  = (ax2 - ax1) * (ay2 - ay1);
        float iw  = fmaxf(fminf(ax2, tx2) - fmaxf(ax1, tx1), 0.f);
        float ih  = fmaxf(fminf(ay2, ty2) - fmaxf(ay1, ty1), 0.f);
        float inter1 = iw * ih;
        float iou1   = inter1 / (a1 + ta - inter1);

        // box2 iou
        float bx1 = x2 * invS - 0.5f * w2, by1 = y2 * invS - 0.5f * h2;
        float bx2 = x2 * invS + 0.5f * w2, by2 = y2 * invS + 0.5f * h2;
        float a2  = (bx2 - bx1) * (by2 - by1);
        float jw  = fmaxf(fminf(bx2, tx2) - fmaxf(bx1, tx1), 0.f);
        float jh  = fmaxf(fminf(by2, ty2) - fmaxf(by1, ty1), 0.f);
        float inter2 = jw * jh;
        float iou2   = inter2 / (a2 + ta - inter2);

        bool  t1   = iou1 > iou2;
        float bx   = t1 ? x1 : x2,  by = t1 ? y1 : y2;
        float bw   = t1 ? w1 : w2,  bh = t1 ? h1 : h2;
        float bc   = t1 ? c1 : c2;
        float biou = t1 ? iou1 : iou2;

        float dx = bx - tb.x, dy = by - tb.y;
        float dw = sqrtf(bw) - sqrtf(tb.z);
        float dh = sqrtf(bh) - sqrtf(tb.w);
        acc_reg  = o * (dx*dx + dy*dy + dw*dw + dh*dh);
        float dc = bc - biou;
        acc_cont = o * dc * dc;
    }

    // ---- reduction: wave shuffle -> LDS -> atomics ----
    #pragma unroll
    for (int off = 32; off > 0; off >>= 1) {
        acc_reg   += __shfl_down(acc_reg,   off);
        acc_cont  += __shfl_down(acc_cont,  off);
        acc_noobj += __shfl_down(acc_noobj, off);
        acc_cls   += __shfl_down(acc_cls,   off);
    }
    const int wave = tid >> 6, lane = tid & 63;
    if (lane == 0) {
        red[wave][0] = acc_reg;
        red[wave][1] = acc_cont;
        red[wave][2] = acc_noobj;
        red[wave][3] = acc_cls;
    }
    __syncthreads();
    if (tid == 0) {
        float r = 0.f, c = 0.f, n = 0.f, cl = 0.f;
        #pragma unroll
        for (int w = 0; w < 4; ++w) {
            r  += red[w][0];
            c  += red[w][1];
            n  += red[w][2];
            cl += red[w][3];
        }
        const float invN = 1.0f / (float)NBATCH;
        atomicAdd(&ws[0], L_COORD * r  * invN);
        atomicAdd(&ws[1],           c  * invN);
        atomicAdd(&ws[2], L_NOOBJ * n  * invN);
        atomicAdd(&ws[3],           cl * invN);
    }
}

__global__ void yolo_final(const float* __restrict__ ws, float* __restrict__ out) {
    float r = ws[0], c = ws[1], n = ws[2], cl = ws[3];
    out[0] = r + c + n + cl;  // total
    out[1] = r;               // reg_loss
    out[2] = c;               // contain_loss
    out[3] = n;               // no_obj_loss
    out[4] = cl;              // cls_loss
}

extern "C" void kernel_launch(void* const* d_in, const int* in_sizes, int n_in,
                              void* d_out, int out_size, void* d_ws, size_t ws_size,
                              hipStream_t stream) {
    const float* pred   = (const float*)d_in[0];
    const float* tbox   = (const float*)d_in[1];
    const float* tcls   = (const float*)d_in[2];
    const int*   objmap = (const int*)  d_in[3];
    float* ws  = (float*)d_ws;
    float* out = (float*)d_out;

    hipMemsetAsync(ws, 0, 4 * sizeof(float), stream);
    yolo_main<<<NBLK, 256, 0, stream>>>(pred, tbox, tcls, objmap, ws);
    yolo_final<<<1, 1, 0, stream>>>(ws, out);
}

// Round 2
// 209.041 us; speedup vs baseline: 1.5509x; 1.5509x over previous
//
#include <hip/hip_runtime.h>

// YOLO-v1 loss, N=4096, S=14 grid, 30 channels/cell.
// Memory-bound streaming reduction: ~176 MB in, 5 floats out. HBM floor <28us.
// R1: replaced same-address atomicAdd fan-in (3136 blocks x 4 atomics to one
// cache line -> ~150us serialized chain, all pipes idle) with per-block
// float4 partial stores + separate reduce kernel.

#define NBATCH   4096
#define SGRID    14
#define CELLS    (NBATCH * SGRID * SGRID)   // 802816
#define CPB      256                        // cells per block (divides CELLS exactly)
#define NBLK     (CELLS / CPB)              // 3136
#define L_COORD  5.0f
#define L_NOOBJ  0.5f

__global__ __launch_bounds__(256) void yolo_main(
    const float* __restrict__ pred,    // [CELLS][30]
    const float* __restrict__ tbox,    // [CELLS][4]
    const float* __restrict__ tcls,    // [CELLS][20]
    const int*   __restrict__ objmap,  // [CELLS] (bool as int32)
    float4*      __restrict__ part)    // [NBLK]: (reg, contain, noobj, cls) unscaled
{
    __shared__ float lds_pred[CPB * 30];   // 30720 B
    __shared__ float lds_obj[CPB];
    __shared__ float red[4][4];            // [wave][term]

    const int tid  = threadIdx.x;
    const int blk  = blockIdx.x;
    const int base = blk * CPB;

    // ---- stage pred tile: 1920 float4, fully coalesced ----
    {
        const float4* p4  = (const float4*)pred + (size_t)blk * (CPB * 30 / 4);
        float4*       lp4 = (float4*)lds_pred;
        for (int i = tid; i < CPB * 30 / 4; i += 256)   // 7-8 iters
            lp4[i] = p4[i];
    }
    lds_obj[tid] = objmap[base + tid] ? 1.0f : 0.0f;
    __syncthreads();

    float acc_reg = 0.f, acc_cont = 0.f, acc_noobj = 0.f, acc_cls = 0.f;

    // ---- cls pass: coalesced float4 stream over target_cls ----
    {
        const float4* c4 = (const float4*)tcls + (size_t)blk * (CPB * 20 / 4);
        for (int i = tid; i < CPB * 20 / 4; i += 256) {  // exactly 5 iters
            float4 t  = c4[i];
            int cell  = i / 5;                // 5 float4 per cell (20 ch)
            int ch0   = (i - cell * 5) * 4;
            float o   = lds_obj[cell];
            const float* pc = &lds_pred[cell * 30 + 10 + ch0];
            float d0 = pc[0] - t.x, d1 = pc[1] - t.y;
            float d2 = pc[2] - t.z, d3 = pc[3] - t.w;
            acc_cls += o * (d0*d0 + d1*d1 + d2*d2 + d3*d3);
        }
    }

    // ---- per-cell pass: boxes / iou / noobj ----
    {
        const float* pp = &lds_pred[tid * 30];  // stride 30 -> 2-way bank alias (free)
        float x1 = pp[0], y1 = pp[1], w1 = pp[2], h1 = pp[3], c1 = pp[4];
        float x2 = pp[5], y2 = pp[6], w2 = pp[7], h2 = pp[8], c2 = pp[9];
        float o  = lds_obj[tid];
        float no = 1.0f - o;
        acc_noobj = no * (c1*c1 + c2*c2);

        float4 tb = ((const float4*)tbox)[base + tid];  // coalesced
        const float invS = 1.0f / 14.0f;

        // target xyxy
        float txc = tb.x * invS, tyc = tb.y * invS;
        float tx1 = txc - 0.5f * tb.z, ty1 = tyc - 0.5f * tb.w;
        float tx2 = txc + 0.5f * tb.z, ty2 = tyc + 0.5f * tb.w;
        float ta  = (tx2 - tx1) * (ty2 - ty1);

        // box1 iou
        float ax1 = x1 * invS - 0.5f * w1, ay1 = y1 * invS - 0.5f * h1;
        float ax2 = x1 * invS + 0.5f * w1, ay2 = y1 * invS + 0.5f * h1;
        float a1  = (ax2 - ax1) * (ay2 - ay1);
        float iw  = fmaxf(fminf(ax2, tx2) - fmaxf(ax1, tx1), 0.f);
        float ih  = fmaxf(fminf(ay2, ty2) - fmaxf(ay1, ty1), 0.f);
        float inter1 = iw * ih;
        float iou1   = inter1 / (a1 + ta - inter1);

        // box2 iou
        float bx1 = x2 * invS - 0.5f * w2, by1 = y2 * invS - 0.5f * h2;
        float bx2 = x2 * invS + 0.5f * w2, by2 = y2 * invS + 0.5f * h2;
        float a2  = (bx2 - bx1) * (by2 - by1);
        float jw  = fmaxf(fminf(bx2, tx2) - fmaxf(bx1, tx1), 0.f);
        float jh  = fmaxf(fminf(by2, ty2) - fmaxf(by1, ty1), 0.f);
        float inter2 = jw * jh;
        float iou2   = inter2 / (a2 + ta - inter2);

        bool  t1   = iou1 > iou2;
        float bx   = t1 ? x1 : x2,  by = t1 ? y1 : y2;
        float bw   = t1 ? w1 : w2,  bh = t1 ? h1 : h2;
        float bc   = t1 ? c1 : c2;
        float biou = t1 ? iou1 : iou2;

        float dx = bx - tb.x, dy = by - tb.y;
        float dw = sqrtf(bw) - sqrtf(tb.z);
        float dh = sqrtf(bh) - sqrtf(tb.w);
        acc_reg  = o * (dx*dx + dy*dy + dw*dw + dh*dh);
        float dc = bc - biou;
        acc_cont = o * dc * dc;
    }

    // ---- reduction: wave shuffle -> LDS -> one float4 store per block ----
    #pragma unroll
    for (int off = 32; off > 0; off >>= 1) {
        acc_reg   += __shfl_down(acc_reg,   off);
        acc_cont  += __shfl_down(acc_cont,  off);
        acc_noobj += __shfl_down(acc_noobj, off);
        acc_cls   += __shfl_down(acc_cls,   off);
    }
    const int wave = tid >> 6, lane = tid & 63;
    if (lane == 0) {
        red[wave][0] = acc_reg;
        red[wave][1] = acc_cont;
        red[wave][2] = acc_noobj;
        red[wave][3] = acc_cls;
    }
    __syncthreads();
    if (tid == 0) {
        float4 p;
        p.x = red[0][0] + red[1][0] + red[2][0] + red[3][0];
        p.y = red[0][1] + red[1][1] + red[2][1] + red[3][1];
        p.z = red[0][2] + red[1][2] + red[2][2] + red[3][2];
        p.w = red[0][3] + red[1][3] + red[2][3] + red[3][3];
        part[blk] = p;   // contention-free
    }
}

__global__ __launch_bounds__(1024) void yolo_reduce(
    const float4* __restrict__ part, float* __restrict__ out)
{
    __shared__ float red[16][4];
    float r = 0.f, c = 0.f, n = 0.f, cl = 0.f;
    for (int i = threadIdx.x; i < NBLK; i += 1024) {
        float4 p = part[i];
        r += p.x; c += p.y; n += p.z; cl += p.w;
    }
    #pragma unroll
    for (int off = 32; off > 0; off >>= 1) {
        r  += __shfl_down(r,  off);
        c  += __shfl_down(c,  off);
        n  += __shfl_down(n,  off);
        cl += __shfl_down(cl, off);
    }
    const int wave = threadIdx.x >> 6, lane = threadIdx.x & 63;
    if (lane == 0) {
        red[wave][0] = r; red[wave][1] = c; red[wave][2] = n; red[wave][3] = cl;
    }
    __syncthreads();
    if (threadIdx.x == 0) {
        float R = 0.f, C = 0.f, Nn = 0.f, Cl = 0.f;
        #pragma unroll
        for (int w = 0; w < 16; ++w) {
            R += red[w][0]; C += red[w][1]; Nn += red[w][2]; Cl += red[w][3];
        }
        const float invN = 1.0f / (float)NBATCH;
        float reg   = L_COORD * R  * invN;
        float cont  =           C  * invN;
        float noobj = L_NOOBJ * Nn * invN;
        float cls   =           Cl * invN;
        out[0] = reg + cont + noobj + cls;
        out[1] = reg;
        out[2] = cont;
        out[3] = noobj;
        out[4] = cls;
    }
}

extern "C" void kernel_launch(void* const* d_in, const int* in_sizes, int n_in,
                              void* d_out, int out_size, void* d_ws, size_t ws_size,
                              hipStream_t stream) {
    const float* pred   = (const float*)d_in[0];
    const float* tbox   = (const float*)d_in[1];
    const float* tcls   = (const float*)d_in[2];
    const int*   objmap = (const int*)  d_in[3];
    float4* part = (float4*)d_ws;      // NBLK * 16 B = 50 KB, all slots written
    float*  out  = (float*)d_out;

    yolo_main<<<NBLK, 256, 0, stream>>>(pred, tbox, tcls, objmap, part);
    yolo_reduce<<<1, 1024, 0, stream>>>(part, out);
}